// Round 1
// baseline (390.765 us; speedup 1.0000x reference)
//
#include <hip/hip_runtime.h>
#include <hip/hip_bf16.h>
#include <type_traits>

// ---------------- problem constants ----------------
static constexpr int BATCH = 2;
static constexpr int T     = 4096;
static constexpr int F     = 256;
static constexpr int M     = BATCH * T;   // 8192 rows
static constexpr int K     = 256;         // inner dim of all big GEMMs
static constexpr int HPS   = 4;           // heads per scale
static constexpr int CTX0  = 31, CTX1 = 61;
static constexpr int N2_0  = HPS * CTX0;  // 124
static constexpr int N2_1  = HPS * CTX1;  // 244

typedef short bf16x8 __attribute__((ext_vector_type(8)));
typedef float f32x4  __attribute__((ext_vector_type(4)));

__device__ __forceinline__ ushort f2bf(float f) {
    union { float f; uint u; } v; v.f = f;
    uint u = v.u;
    uint r = (u + 0x7fffu + ((u >> 16) & 1u)) >> 16;   // round-nearest-even
    return (ushort)r;
}
__device__ __forceinline__ float bf2f(ushort u) {
    union { uint u; float f; } v; v.u = ((uint)u) << 16;
    return v.f;
}

// ---------------- fp32 -> bf16 conversion (9 segments) ----------------
struct CvtArgs {
    const float* src[9];
    ushort*      dst[9];
    int          n[9];
};

__global__ __launch_bounds__(256) void cvt_kernel(CvtArgs a) {
    int seg = blockIdx.y;
    int n = a.n[seg];
    int i = (blockIdx.x * 256 + threadIdx.x) * 4;
    if (i >= n) return;
    float4 v = *reinterpret_cast<const float4*>(a.src[seg] + i);
    ushort4 o;
    o.x = f2bf(v.x); o.y = f2bf(v.y); o.z = f2bf(v.z); o.w = f2bf(v.w);
    *reinterpret_cast<ushort4*>(a.dst[seg] + i) = o;
}

// ---------------- bf16 MFMA GEMM: C[M,N] = act(A[M,K] @ B[K,N]) ----------------
// 64x64 tile, 256 threads = 4 waves (2x2), each wave 32x32 = 2x2 16x16 frags.
// B panel (K x 64) staged transposed once; A tile (64 x 32) staged per K-step.
template <typename OutT, bool RELU>
__global__ __launch_bounds__(256) void gemm_kernel(
    const ushort* __restrict__ A,   // [M][K] bf16
    const ushort* __restrict__ Bw,  // [K][N] bf16
    OutT* __restrict__ C,           // [M][N]
    int N)
{
    constexpr int BM = 64, BN = 64, BK = 32;
    constexpr int LDA = BK + 8;     // 40 elts -> 80B row stride (16B aligned, 2-way banks)
    constexpr int LDB = K + 8;      // 264 elts -> 528B row stride (16B aligned, 2-way banks)
    __shared__ ushort Alds[BM][LDA];     // 5.0 KB
    __shared__ ushort Btl [BN][LDB];     // 33.0 KB   (Btl[n][k] = B[k][n0+n])

    const int tid = threadIdx.x;
    const int m0 = blockIdx.x * BM;
    const int n0 = blockIdx.y * BN;

    // stage full B panel, transposed, zero-padded past N
    for (int idx = tid; idx < BN * K; idx += 256) {
        int n = idx & (BN - 1);
        int k = idx >> 6;
        ushort val = 0;
        if (n0 + n < N) val = Bw[k * N + n0 + n];
        Btl[n][k] = val;
    }

    const int wave = tid >> 6, lane = tid & 63;
    const int wr = wave >> 1, wc = wave & 1;
    const int l15 = lane & 15, l4 = lane >> 4;

    f32x4 acc[2][2] = {};
    __syncthreads();

    for (int k0 = 0; k0 < K; k0 += BK) {
        // stage A tile: 64 rows x 32 k, 16B per thread
        {
            int row = tid >> 2;
            int kk  = (tid & 3) * 8;
            bf16x8 v = *reinterpret_cast<const bf16x8*>(A + (m0 + row) * K + k0 + kk);
            *reinterpret_cast<bf16x8*>(&Alds[row][kk]) = v;
        }
        __syncthreads();

        bf16x8 af[2], bfr[2];
#pragma unroll
        for (int i = 0; i < 2; i++) {
            int row = wr * 32 + i * 16 + l15;
            af[i] = *reinterpret_cast<const bf16x8*>(&Alds[row][l4 * 8]);
        }
#pragma unroll
        for (int j = 0; j < 2; j++) {
            int col = wc * 32 + j * 16 + l15;
            bfr[j] = *reinterpret_cast<const bf16x8*>(&Btl[col][k0 + l4 * 8]);
        }
#pragma unroll
        for (int i = 0; i < 2; i++)
#pragma unroll
            for (int j = 0; j < 2; j++)
                acc[i][j] = __builtin_amdgcn_mfma_f32_16x16x32_bf16(af[i], bfr[j], acc[i][j], 0, 0, 0);
        __syncthreads();
    }

    // epilogue: C/D layout col = lane&15, row = (lane>>4)*4 + reg  (m89-verified)
#pragma unroll
    for (int i = 0; i < 2; i++)
#pragma unroll
        for (int j = 0; j < 2; j++) {
            int col = n0 + wc * 32 + j * 16 + l15;
            if (col < N) {
#pragma unroll
                for (int r = 0; r < 4; r++) {
                    int row = m0 + wr * 32 + i * 16 + l4 * 4 + r;
                    float v = acc[i][j][r];
                    if (RELU) v = fmaxf(v, 0.0f);
                    if constexpr (std::is_same<OutT, ushort>::value)
                        C[row * N + col] = f2bf(v);
                    else
                        C[row * N + col] = v;
                }
            }
        }
}

// ---------------- windowed attention + scale combine ----------------
// one block per (b,t); threads 0..7 do the 8 per-head softmaxes, then
// all 256 threads accumulate the windowed weighted sums over v0/v1.
__global__ __launch_bounds__(256) void attn_kernel(
    const float*  __restrict__ lg0,   // [M][124]
    const float*  __restrict__ lg1,   // [M][244]
    const ushort* __restrict__ v0,    // [M][256] bf16
    const ushort* __restrict__ v1,    // [M][256] bf16
    const float*  __restrict__ scale_w,
    ushort*       __restrict__ outc)  // [M][256] bf16
{
    const int bt = blockIdx.x;
    const int b = bt / T, t = bt & (T - 1);
    const int tid = threadIdx.x;

    __shared__ float att0[HPS][CTX0];
    __shared__ float att1[HPS][CTX1];

    if (tid < 8) {
        int scale = tid >> 2, h = tid & 3;
        if (scale == 0) {
            const float* lp = lg0 + (size_t)bt * N2_0 + h * CTX0;
            float mx = -1e30f;
            for (int c = 0; c < CTX0; c++) mx = fmaxf(mx, lp[c]);
            float s = 0.f;
            for (int c = 0; c < CTX0; c++) { float e = expf(lp[c] - mx); att0[h][c] = e; s += e; }
            float inv = 1.0f / s;
            for (int c = 0; c < CTX0; c++) att0[h][c] *= inv;
        } else {
            const float* lp = lg1 + (size_t)bt * N2_1 + h * CTX1;
            float mx = -1e30f;
            for (int c = 0; c < CTX1; c++) mx = fmaxf(mx, lp[c]);
            float s = 0.f;
            for (int c = 0; c < CTX1; c++) { float e = expf(lp[c] - mx); att1[h][c] = e; s += e; }
            float inv = 1.0f / s;
            for (int c = 0; c < CTX1; c++) att1[h][c] *= inv;
        }
    }
    __syncthreads();

    // softmax over the two scale weights
    float s0 = scale_w[0], s1 = scale_w[1];
    float mx = fmaxf(s0, s1);
    float e0 = expf(s0 - mx), e1 = expf(s1 - mx);
    float sw0 = e0 / (e0 + e1), sw1 = e1 / (e0 + e1);

    const int f = tid;
    const int h = f >> 6;
    float acc0 = 0.f, acc1 = 0.f;

#pragma unroll 1
    for (int c = 0; c < CTX0; c++) {
        int tt = t + c - (CTX0 - 1) / 2;
        if ((unsigned)tt < (unsigned)T)
            acc0 += att0[h][c] * bf2f(v0[(size_t)(b * T + tt) * F + f]);
    }
#pragma unroll 1
    for (int c = 0; c < CTX1; c++) {
        int tt = t + c - (CTX1 - 1) / 2;
        if ((unsigned)tt < (unsigned)T)
            acc1 += att1[h][c] * bf2f(v1[(size_t)(b * T + tt) * F + f]);
    }

    outc[(size_t)bt * F + f] = f2bf(sw0 * acc0 + sw1 * acc1);
}

// ---------------- host launcher ----------------
extern "C" void kernel_launch(void* const* d_in, const int* in_sizes, int n_in,
                              void* d_out, int out_size, void* d_ws, size_t ws_size,
                              hipStream_t stream)
{
    const float* Q    = (const float*)d_in[0];
    // d_in[1] = key (unused by the reference)
    const float* V    = (const float*)d_in[2];
    const float* W1_0 = (const float*)d_in[3];
    const float* W1_1 = (const float*)d_in[4];
    const float* W2_0 = (const float*)d_in[5];
    const float* W2_1 = (const float*)d_in[6];
    const float* W3_0 = (const float*)d_in[7];
    const float* W3_1 = (const float*)d_in[8];
    const float* SW   = (const float*)d_in[9];
    const float* WO   = (const float*)d_in[10];

    // ---- carve workspace (all sizes 16B-multiples) ----
    char* p = (char*)d_ws;
    auto carve = [&](size_t bytes) { char* r = p; p += bytes; return r; };
    ushort* qbf  = (ushort*)carve((size_t)M * K * 2);
    ushort* vbf  = (ushort*)carve((size_t)M * K * 2);
    ushort* w1b0 = (ushort*)carve((size_t)K * F * 2);
    ushort* w1b1 = (ushort*)carve((size_t)K * F * 2);
    ushort* w2b0 = (ushort*)carve((size_t)K * N2_0 * 2);
    ushort* w2b1 = (ushort*)carve((size_t)K * N2_1 * 2);
    ushort* w3b0 = (ushort*)carve((size_t)K * F * 2);
    ushort* w3b1 = (ushort*)carve((size_t)K * F * 2);
    ushort* wob  = (ushort*)carve((size_t)K * F * 2);
    ushort* q0b  = (ushort*)carve((size_t)M * F * 2);
    ushort* q1b  = (ushort*)carve((size_t)M * F * 2);
    float*  lg0  = (float*)carve((size_t)M * N2_0 * 4);
    float*  lg1  = (float*)carve((size_t)M * N2_1 * 4);
    ushort* v0b  = (ushort*)carve((size_t)M * F * 2);
    ushort* v1b  = (ushort*)carve((size_t)M * F * 2);
    ushort* ocb  = (ushort*)carve((size_t)M * F * 2);
    (void)ws_size;

    // ---- 1) convert all fp32 inputs to bf16 ----
    CvtArgs ca;
    const float* srcs[9] = { Q, V, W1_0, W1_1, W2_0, W2_1, W3_0, W3_1, WO };
    ushort*      dsts[9] = { qbf, vbf, w1b0, w1b1, w2b0, w2b1, w3b0, w3b1, wob };
    int          ns  [9] = { M*K, M*K, K*F, K*F, K*N2_0, K*N2_1, K*F, K*F, K*F };
    for (int i = 0; i < 9; i++) { ca.src[i] = srcs[i]; ca.dst[i] = dsts[i]; ca.n[i] = ns[i]; }
    {
        dim3 g((M * K / 4 + 255) / 256, 9);
        cvt_kernel<<<g, 256, 0, stream>>>(ca);
    }

    auto gemm_grid = [](int N) { return dim3(M / 64, (N + 63) / 64); };

    // ---- 2) q_s = relu(Q @ W1_s) ----
    gemm_kernel<ushort, true ><<<gemm_grid(F), 256, 0, stream>>>(qbf, w1b0, q0b, F);
    gemm_kernel<ushort, true ><<<gemm_grid(F), 256, 0, stream>>>(qbf, w1b1, q1b, F);

    // ---- 3) logits_s = q_s @ W2_s ----
    gemm_kernel<float,  false><<<gemm_grid(N2_0), 256, 0, stream>>>(q0b, w2b0, lg0, N2_0);
    gemm_kernel<float,  false><<<gemm_grid(N2_1), 256, 0, stream>>>(q1b, w2b1, lg1, N2_1);

    // ---- 4) v_s = V @ W3_s ----
    gemm_kernel<ushort, false><<<gemm_grid(F), 256, 0, stream>>>(vbf, w3b0, v0b, F);
    gemm_kernel<ushort, false><<<gemm_grid(F), 256, 0, stream>>>(vbf, w3b1, v1b, F);

    // ---- 5) softmax + windowed sum + scale combine ----
    attn_kernel<<<M, 256, 0, stream>>>(lg0, lg1, v0b, v1b, SW, ocb);

    // ---- 6) final @ w_out ----
    gemm_kernel<float,  false><<<gemm_grid(F), 256, 0, stream>>>(ocb, wob, (float*)d_out, F);
}

// Round 2
// 173.167 us; speedup vs baseline: 2.2566x; 2.2566x over previous
//
#include <hip/hip_runtime.h>
#include <hip/hip_bf16.h>
#include <type_traits>

// ---------------- problem constants ----------------
static constexpr int BATCH = 2;
static constexpr int T     = 4096;
static constexpr int F     = 256;
static constexpr int M     = BATCH * T;   // 8192 rows
static constexpr int K     = 256;         // inner dim of all GEMMs
static constexpr int HPS   = 4;           // heads per scale
static constexpr int CTX0  = 31, CTX1 = 61;
static constexpr int N2_0  = HPS * CTX0;  // 124
static constexpr int N2_1  = HPS * CTX1;  // 244

typedef short bf16x8 __attribute__((ext_vector_type(8)));
typedef float f32x4  __attribute__((ext_vector_type(4)));

__device__ __forceinline__ ushort f2bf(float f) {
    union { float f; uint u; } v; v.f = f;
    uint u = v.u;
    return (ushort)((u + 0x7fffu + ((u >> 16) & 1u)) >> 16);   // RNE
}
__device__ __forceinline__ float bf2f(ushort u) {
    union { uint u; float f; } v; v.u = ((uint)u) << 16;
    return v.f;
}

// ---------------- weight convert + transpose (one tiny kernel) ----------------
// Builds wt[1648][256] bf16 where rows are:
//   [0,512)    : W1cat^T  (n<256 -> W1_0[:,n], else W1_1[:,n-256])
//   [512,636)  : W2_0^T   (124 rows)
//   [636,880)  : W2_1^T   (244 rows)
//   [880,1392) : W3cat^T
//   [1392,1648): WO^T
struct WcvtArgs {
    const float* w1_0; const float* w1_1;
    const float* w2_0; const float* w2_1;
    const float* w3_0; const float* w3_1;
    const float* wo;
    ushort* wt;
};
static constexpr int WT_ROWS = 512 + N2_0 + N2_1 + 512 + 256;  // 1648

__global__ __launch_bounds__(256) void wcvt_kernel(WcvtArgs a) {
    int gid = blockIdx.x * 256 + threadIdx.x;
    if (gid >= WT_ROWS * (K / 8)) return;
    int row = gid >> 5;            // K/8 == 32 chunks per row
    int kk  = (gid & 31) * 8;

    const float* src; int stride, col;
    if (row < 512) {
        int n = row;
        if (n < 256) { src = a.w1_0; col = n; } else { src = a.w1_1; col = n - 256; }
        stride = 256;
    } else if (row < 512 + N2_0) {
        src = a.w2_0; col = row - 512; stride = N2_0;
    } else if (row < 512 + N2_0 + N2_1) {
        src = a.w2_1; col = row - (512 + N2_0); stride = N2_1;
    } else if (row < 512 + N2_0 + N2_1 + 512) {
        int n = row - (512 + N2_0 + N2_1);
        if (n < 256) { src = a.w3_0; col = n; } else { src = a.w3_1; col = n - 256; }
        stride = 256;
    } else {
        src = a.wo; col = row - (512 + N2_0 + N2_1 + 512); stride = 256;
    }

    ushort o[8];
#pragma unroll
    for (int j = 0; j < 8; j++) o[j] = f2bf(src[(size_t)(kk + j) * stride + col]);
    *reinterpret_cast<bf16x8*>(a.wt + (size_t)row * K + kk) =
        *reinterpret_cast<bf16x8*>(o);
}

// ---------------- bf16 MFMA GEMM: C[M,N] = act(A[M,K] @ Bt[N,K]^T) ----------------
// A may be fp32 (converted during LDS staging) or bf16. Bt is pre-transposed [N][K].
// 64x64 tile, 256 threads = 4 waves (2x2), each wave 32x32 = 2x2 16x16 frags.
template <typename InT, typename OutT, bool RELU>
__global__ __launch_bounds__(256) void gemm_kernel(
    const InT*    __restrict__ A,   // [M][lda]
    int lda,
    const ushort* __restrict__ Bt,  // [N][K] bf16 (transposed weight)
    OutT*         __restrict__ C,   // [M][N]
    int N)
{
    constexpr int BM = 64, BN = 64, BK = 32;
    constexpr int LDA = BK + 8;     // 40 elts = 80B rows (16B aligned)
    constexpr int LDB = K + 8;      // 264 elts = 528B rows (16B aligned)
    __shared__ ushort Alds[BM][LDA];     // 5 KB
    __shared__ ushort Btl [BN][LDB];     // 33 KB

    const int tid = threadIdx.x;
    const int m0 = blockIdx.x * BM;
    const int n0 = blockIdx.y * BN;

    // stage full B panel: vectorized 16B loads, zero-pad rows past N
    for (int idx = tid; idx < BN * (K / 8); idx += 256) {
        int n  = idx >> 5;          // K/8 == 32
        int kk = (idx & 31) * 8;
        bf16x8 v = {};
        if (n0 + n < N)
            v = *reinterpret_cast<const bf16x8*>(Bt + (size_t)(n0 + n) * K + kk);
        *reinterpret_cast<bf16x8*>(&Btl[n][kk]) = v;
    }

    const int wave = tid >> 6, lane = tid & 63;
    const int wr = wave >> 1, wc = wave & 1;
    const int l15 = lane & 15, l4 = lane >> 4;

    f32x4 acc[2][2] = {};
    __syncthreads();

    for (int k0 = 0; k0 < K; k0 += BK) {
        // stage A tile 64x32 (8 elems / thread)
        {
            int row = tid >> 2;
            int kk  = (tid & 3) * 8;
            const InT* ap = A + (size_t)(m0 + row) * lda + k0 + kk;
            if constexpr (std::is_same<InT, float>::value) {
                float4 v0 = *reinterpret_cast<const float4*>(ap);
                float4 v1 = *reinterpret_cast<const float4*>(ap + 4);
                ushort o[8] = { f2bf(v0.x), f2bf(v0.y), f2bf(v0.z), f2bf(v0.w),
                                f2bf(v1.x), f2bf(v1.y), f2bf(v1.z), f2bf(v1.w) };
                *reinterpret_cast<bf16x8*>(&Alds[row][kk]) = *reinterpret_cast<bf16x8*>(o);
            } else {
                *reinterpret_cast<bf16x8*>(&Alds[row][kk]) =
                    *reinterpret_cast<const bf16x8*>(ap);
            }
        }
        __syncthreads();

        bf16x8 af[2], bfr[2];
#pragma unroll
        for (int i = 0; i < 2; i++)
            af[i] = *reinterpret_cast<const bf16x8*>(&Alds[wr * 32 + i * 16 + l15][l4 * 8]);
#pragma unroll
        for (int j = 0; j < 2; j++)
            bfr[j] = *reinterpret_cast<const bf16x8*>(&Btl[wc * 32 + j * 16 + l15][k0 + l4 * 8]);
#pragma unroll
        for (int i = 0; i < 2; i++)
#pragma unroll
            for (int j = 0; j < 2; j++)
                acc[i][j] = __builtin_amdgcn_mfma_f32_16x16x32_bf16(af[i], bfr[j], acc[i][j], 0, 0, 0);
        __syncthreads();
    }

    // epilogue: C/D layout col = lane&15, row = (lane>>4)*4 + reg  (m89-verified)
#pragma unroll
    for (int i = 0; i < 2; i++)
#pragma unroll
        for (int j = 0; j < 2; j++) {
            int col = n0 + wc * 32 + j * 16 + l15;
            if (col < N) {
#pragma unroll
                for (int r = 0; r < 4; r++) {
                    int row = m0 + wr * 32 + i * 16 + l4 * 4 + r;
                    float v = acc[i][j][r];
                    if (RELU) v = fmaxf(v, 0.0f);
                    if constexpr (std::is_same<OutT, ushort>::value)
                        C[(size_t)row * N + col] = f2bf(v);
                    else
                        C[(size_t)row * N + col] = v;
                }
            }
        }
}

// ---------------- windowed attention + scale combine ----------------
// 8 tokens / block (256 threads). Phase 1: 64 softmax tasks x 4-lane groups
// (shfl_xor reduce). Phase 2: thread = (token, 8 features), bf16x8 loads.
__global__ __launch_bounds__(256) void attn_kernel(
    const float*  __restrict__ lg0,   // [M][124]
    const float*  __restrict__ lg1,   // [M][244]
    const ushort* __restrict__ v01,   // [M][512] bf16 (v0 | v1)
    const float*  __restrict__ scale_w,
    ushort*       __restrict__ outc)  // [M][256] bf16
{
    const int bt0 = blockIdx.x * 8;
    const int tid = threadIdx.x;

    // attw[tok][0..123]   = sw0 * att0[h][c]   (h*31 + c)
    // attw[tok][124..367] = sw1 * att1[h][c]   (124 + h*61 + c)
    __shared__ float attw[8][368];

    // softmax over the two scale weights (cheap, every thread)
    float s0 = scale_w[0], s1 = scale_w[1];
    float mxs = fmaxf(s0, s1);
    float e0 = __expf(s0 - mxs), e1 = __expf(s1 - mxs);
    float sw0 = e0 / (e0 + e1), sw1 = e1 / (e0 + e1);

    // ---- phase 1: 64 tasks (8 tok x 2 scale x 4 head), 4 lanes each ----
    {
        int task = tid >> 2, sub = tid & 3;
        int tok = task >> 3, rest = task & 7;
        int scale = rest >> 2, h = rest & 3;
        int bt = bt0 + tok;
        const float* lp;
        float* dst;
        int ctx;
        float sw;
        if (scale == 0) {
            lp  = lg0 + (size_t)bt * N2_0 + h * CTX0;
            dst = &attw[tok][h * CTX0];
            ctx = CTX0; sw = sw0;
        } else {
            lp  = lg1 + (size_t)bt * N2_1 + h * CTX1;
            dst = &attw[tok][124 + h * CTX1];
            ctx = CTX1; sw = sw1;
        }
        float mx = -1e30f;
        for (int c = sub; c < ctx; c += 4) mx = fmaxf(mx, lp[c]);
        mx = fmaxf(mx, __shfl_xor(mx, 1));
        mx = fmaxf(mx, __shfl_xor(mx, 2));
        float s = 0.f;
        for (int c = sub; c < ctx; c += 4) {
            float e = __expf(lp[c] - mx);
            dst[c] = e;
            s += e;
        }
        s += __shfl_xor(s, 1);
        s += __shfl_xor(s, 2);
        float scl = sw / s;
        for (int c = sub; c < ctx; c += 4) dst[c] *= scl;
    }
    __syncthreads();

    // ---- phase 2: windowed weighted sums, 16B vector loads ----
    const int tok = tid >> 5;
    const int f0  = (tid & 31) * 8;
    const int h   = f0 >> 6;
    const int bt  = bt0 + tok;
    const int b   = bt >> 12;           // /T
    const int t   = bt & (T - 1);

    float acc[8] = {};
    const float* a0 = &attw[tok][h * CTX0];
    const float* a1 = &attw[tok][124 + h * CTX1];

#pragma unroll 4
    for (int c = 0; c < CTX0; c++) {
        int tt = t + c - (CTX0 - 1) / 2;
        if ((unsigned)tt < (unsigned)T) {
            bf16x8 v = *reinterpret_cast<const bf16x8*>(
                v01 + ((size_t)(b * T + tt) * 512 + f0));
            float w = a0[c];
#pragma unroll
            for (int j = 0; j < 8; j++) acc[j] += w * bf2f((ushort)v[j]);
        }
    }
#pragma unroll 4
    for (int c = 0; c < CTX1; c++) {
        int tt = t + c - (CTX1 - 1) / 2;
        if ((unsigned)tt < (unsigned)T) {
            bf16x8 v = *reinterpret_cast<const bf16x8*>(
                v01 + ((size_t)(b * T + tt) * 512 + 256 + f0));
            float w = a1[c];
#pragma unroll
            for (int j = 0; j < 8; j++) acc[j] += w * bf2f((ushort)v[j]);
        }
    }

    ushort o[8];
#pragma unroll
    for (int j = 0; j < 8; j++) o[j] = f2bf(acc[j]);
    *reinterpret_cast<bf16x8*>(outc + (size_t)bt * F + f0) =
        *reinterpret_cast<bf16x8*>(o);
}

// ---------------- host launcher ----------------
extern "C" void kernel_launch(void* const* d_in, const int* in_sizes, int n_in,
                              void* d_out, int out_size, void* d_ws, size_t ws_size,
                              hipStream_t stream)
{
    const float* Q    = (const float*)d_in[0];
    const float* V    = (const float*)d_in[2];
    const float* W1_0 = (const float*)d_in[3];
    const float* W1_1 = (const float*)d_in[4];
    const float* W2_0 = (const float*)d_in[5];
    const float* W2_1 = (const float*)d_in[6];
    const float* W3_0 = (const float*)d_in[7];
    const float* W3_1 = (const float*)d_in[8];
    const float* SW   = (const float*)d_in[9];
    const float* WO   = (const float*)d_in[10];

    // ---- carve workspace ----
    char* p = (char*)d_ws;
    auto carve = [&](size_t bytes) { char* r = p; p += (bytes + 255) & ~255ull; return r; };
    ushort* wt   = (ushort*)carve((size_t)WT_ROWS * K * 2);      // 844 KB
    ushort* q01  = (ushort*)carve((size_t)M * 512 * 2);          // 8.4 MB
    float*  lg0  = (float*) carve((size_t)M * N2_0 * 4);         // 4.06 MB
    float*  lg1  = (float*) carve((size_t)M * N2_1 * 4);         // 8.0 MB
    ushort* v01  = (ushort*)carve((size_t)M * 512 * 2);          // 8.4 MB
    ushort* ocb  = (ushort*)carve((size_t)M * F * 2);            // 4.2 MB
    (void)ws_size;

    const ushort* w1t  = wt;                                     // [512][256]
    const ushort* w2t0 = wt + (size_t)512 * K;                   // [124][256]
    const ushort* w2t1 = wt + (size_t)(512 + N2_0) * K;          // [244][256]
    const ushort* w3t  = wt + (size_t)(512 + N2_0 + N2_1) * K;   // [512][256]
    const ushort* wot  = wt + (size_t)(512 + N2_0 + N2_1 + 512) * K; // [256][256]

    // ---- 1) weight convert + transpose ----
    {
        WcvtArgs wa { W1_0, W1_1, W2_0, W2_1, W3_0, W3_1, WO, wt };
        int nthread = WT_ROWS * (K / 8);
        wcvt_kernel<<<(nthread + 255) / 256, 256, 0, stream>>>(wa);
    }

    auto grid = [](int N) { return dim3(M / 64, (N + 63) / 64); };

    // ---- 2) q01 = relu(Q @ [W1_0|W1_1])  (fp32 A, converted in-kernel) ----
    gemm_kernel<float, ushort, true><<<grid(512), 256, 0, stream>>>(Q, K, w1t, q01, 512);

    // ---- 3) logits_s = q_s @ W2_s  (A strided into q01) ----
    gemm_kernel<ushort, float, false><<<grid(N2_0), 256, 0, stream>>>(q01,       512, w2t0, lg0, N2_0);
    gemm_kernel<ushort, float, false><<<grid(N2_1), 256, 0, stream>>>(q01 + 256, 512, w2t1, lg1, N2_1);

    // ---- 4) v01 = V @ [W3_0|W3_1] ----
    gemm_kernel<float, ushort, false><<<grid(512), 256, 0, stream>>>(V, K, w3t, v01, 512);

    // ---- 5) softmax + windowed sum + scale combine ----
    attn_kernel<<<M / 8, 256, 0, stream>>>(lg0, lg1, v01, SW, ocb);

    // ---- 6) final @ w_out ----
    gemm_kernel<ushort, float, false><<<grid(F), 256, 0, stream>>>(ocb, K, wot, (float*)d_out, F);
}

// Round 3
// 170.835 us; speedup vs baseline: 2.2874x; 1.0137x over previous
//
#include <hip/hip_runtime.h>
#include <hip/hip_bf16.h>
#include <type_traits>

// ---------------- problem constants ----------------
static constexpr int BATCH = 2;
static constexpr int T     = 4096;
static constexpr int F     = 256;
static constexpr int M     = BATCH * T;   // 8192 rows
static constexpr int K     = 256;         // inner dim of all GEMMs
static constexpr int HPS   = 4;           // heads per scale
static constexpr int CTX0  = 31, CTX1 = 61;
static constexpr int N2_0  = HPS * CTX0;  // 124
static constexpr int N2_1  = HPS * CTX1;  // 244

typedef short bf16x8 __attribute__((ext_vector_type(8)));
typedef float f32x4  __attribute__((ext_vector_type(4)));

__device__ __forceinline__ ushort f2bf(float f) {
    union { float f; uint u; } v; v.f = f;
    uint u = v.u;
    return (ushort)((u + 0x7fffu + ((u >> 16) & 1u)) >> 16);   // RNE
}
__device__ __forceinline__ float asf(uint u) {
    union { uint u; float f; } v; v.u = u; return v.f;
}

// ---------------- Q/V fp32 -> bf16 ----------------
__global__ __launch_bounds__(256) void cvtqv_kernel(
    const float* __restrict__ q, const float* __restrict__ v,
    ushort* __restrict__ qb, ushort* __restrict__ vb)
{
    const float* src = blockIdx.y ? v : q;
    ushort*      dst = blockIdx.y ? vb : qb;
    size_t i = ((size_t)blockIdx.x * 256 + threadIdx.x) * 8;
    float4 a = *reinterpret_cast<const float4*>(src + i);
    float4 b = *reinterpret_cast<const float4*>(src + i + 4);
    ushort o[8] = { f2bf(a.x), f2bf(a.y), f2bf(a.z), f2bf(a.w),
                    f2bf(b.x), f2bf(b.y), f2bf(b.z), f2bf(b.w) };
    *reinterpret_cast<bf16x8*>(dst + i) = *reinterpret_cast<bf16x8*>(o);
}

// ---------------- weight convert + transpose ----------------
// wt rows: [0,512) W1cat^T | [512,636) W2_0^T | [636,880) W2_1^T
//          [880,1392) W3cat^T | [1392,1648) WO^T      (all [row][K] bf16)
struct WcvtArgs {
    const float* w1_0; const float* w1_1;
    const float* w2_0; const float* w2_1;
    const float* w3_0; const float* w3_1;
    const float* wo;
    ushort* wt;
};
static constexpr int WT_ROWS = 512 + N2_0 + N2_1 + 512 + 256;  // 1648

__global__ __launch_bounds__(256) void wcvt_kernel(WcvtArgs a) {
    int gid = blockIdx.x * 256 + threadIdx.x;
    if (gid >= WT_ROWS * (K / 8)) return;
    int row = gid >> 5;
    int kk  = (gid & 31) * 8;

    const float* src; int stride, col;
    if (row < 512) {
        int n = row;
        if (n < 256) { src = a.w1_0; col = n; } else { src = a.w1_1; col = n - 256; }
        stride = 256;
    } else if (row < 512 + N2_0) {
        src = a.w2_0; col = row - 512; stride = N2_0;
    } else if (row < 512 + N2_0 + N2_1) {
        src = a.w2_1; col = row - (512 + N2_0); stride = N2_1;
    } else if (row < 512 + N2_0 + N2_1 + 512) {
        int n = row - (512 + N2_0 + N2_1);
        if (n < 256) { src = a.w3_0; col = n; } else { src = a.w3_1; col = n - 256; }
        stride = 256;
    } else {
        src = a.wo; col = row - (512 + N2_0 + N2_1 + 512); stride = 256;
    }

    ushort o[8];
#pragma unroll
    for (int j = 0; j < 8; j++) o[j] = f2bf(src[(size_t)(kk + j) * stride + col]);
    *reinterpret_cast<bf16x8*>(a.wt + (size_t)row * K + kk) =
        *reinterpret_cast<bf16x8*>(o);
}

// ---------------- full-K bf16 MFMA GEMM ----------------
// C[M,N] = act(A[M,K] @ Bt[N,K]^T).  64x64 tile, full K=256 staged once,
// XOR-swizzled 16B chunks (conflict-free), single barrier, 32 MFMA/wave.
// 1-D grid with bijective XCD swizzle; cb fastest so one XCD shares A panels.
template <typename OutT, bool RELU>
__global__ __launch_bounds__(256) void gemm_kernel(
    const ushort* __restrict__ A,   // [M][lda] bf16
    int lda,
    const ushort* __restrict__ Bt,  // [N][K] bf16 (pre-transposed weight)
    OutT*         __restrict__ C,   // [M][N]
    int N, int ncb)
{
    __shared__ ushort Al[64][256];   // 32 KB, chunk ch stored at ch^(row&7)
    __shared__ ushort Bl[64][256];   // 32 KB

    const int tid = threadIdx.x;
    const int nwg = gridDim.x;
    const int lin = blockIdx.x;
    const int qq  = nwg >> 3;                       // nwg % 8 == 0 for all our grids
    const int swz = (lin & 7) * qq + (lin >> 3);    // bijective XCD remap
    const int cb  = swz % ncb;
    const int rb  = swz / ncb;
    const int m0  = rb * 64;
    const int n0  = cb * 64;

    // stage A panel: 64 rows x 32 chunks of 16B, swizzled chunk slot
    for (int idx = tid; idx < 64 * 32; idx += 256) {
        int row = idx >> 5, ch = idx & 31;
        bf16x8 v = *reinterpret_cast<const bf16x8*>(A + (size_t)(m0 + row) * lda + ch * 8);
        *reinterpret_cast<bf16x8*>(&Al[row][(ch ^ (row & 7)) * 8]) = v;
    }
    // stage B panel (zero-pad past N)
    for (int idx = tid; idx < 64 * 32; idx += 256) {
        int row = idx >> 5, ch = idx & 31;
        bf16x8 v = {};
        if (n0 + row < N)
            v = *reinterpret_cast<const bf16x8*>(Bt + (size_t)(n0 + row) * K + ch * 8);
        *reinterpret_cast<bf16x8*>(&Bl[row][(ch ^ (row & 7)) * 8]) = v;
    }

    const int wave = tid >> 6, lane = tid & 63;
    const int wr = wave >> 1, wc = wave & 1;
    const int l15 = lane & 15, l4 = lane >> 4;

    f32x4 acc[2][2] = {};
    __syncthreads();

#pragma unroll
    for (int s = 0; s < 8; s++) {
        bf16x8 af[2], bfr[2];
#pragma unroll
        for (int i = 0; i < 2; i++) {
            int row = wr * 32 + i * 16 + l15;
            int ch  = (s * 4 + l4) ^ (row & 7);
            af[i] = *reinterpret_cast<const bf16x8*>(&Al[row][ch * 8]);
        }
#pragma unroll
        for (int j = 0; j < 2; j++) {
            int row = wc * 32 + j * 16 + l15;
            int ch  = (s * 4 + l4) ^ (row & 7);
            bfr[j] = *reinterpret_cast<const bf16x8*>(&Bl[row][ch * 8]);
        }
#pragma unroll
        for (int i = 0; i < 2; i++)
#pragma unroll
            for (int j = 0; j < 2; j++)
                acc[i][j] = __builtin_amdgcn_mfma_f32_16x16x32_bf16(af[i], bfr[j], acc[i][j], 0, 0, 0);
    }

    // epilogue: C/D layout col = lane&15, row = (lane>>4)*4 + reg
#pragma unroll
    for (int i = 0; i < 2; i++)
#pragma unroll
        for (int j = 0; j < 2; j++) {
            int col = n0 + wc * 32 + j * 16 + l15;
            if (col < N) {
#pragma unroll
                for (int r = 0; r < 4; r++) {
                    int row = m0 + wr * 32 + i * 16 + l4 * 4 + r;
                    float v = acc[i][j][r];
                    if (RELU) v = fmaxf(v, 0.0f);
                    if constexpr (std::is_same<OutT, ushort>::value)
                        C[(size_t)row * N + col] = f2bf(v);
                    else
                        C[(size_t)row * N + col] = v;
                }
            }
        }
}

// ---------------- windowed attention + scale combine ----------------
// 8 tokens/block. Stage v0 window (38 rows) + v1 window (68 rows) in LDS
// (zero-padded edges). 64 softmax tasks x 4 lanes. Phase 2 reads LDS only.
__global__ __launch_bounds__(256) void attn_kernel(
    const float*  __restrict__ lg0,   // [M][124]
    const float*  __restrict__ lg1,   // [M][244]
    const ushort* __restrict__ v01,   // [M][512] bf16 (v0 | v1)
    const float*  __restrict__ scale_w,
    ushort*       __restrict__ outc)  // [M][256] bf16
{
    const int tid = threadIdx.x;
    const int nwg = gridDim.x;
    const int lin = blockIdx.x;
    const int qq  = nwg >> 3;
    const int swz = (lin & 7) * qq + (lin >> 3);    // XCD-contiguous tokens
    const int bt0 = swz * 8;
    const int b   = bt0 >> 12;
    const int t0  = bt0 & (T - 1);

    __shared__ float  attw[8][368];   // 11.5 KB  (ctx0: h*31+c | 124 + h*61+c)
    __shared__ ushort v0l[38][256];   // 19 KB    rows t0-15 .. t0+22
    __shared__ ushort v1l[68][256];   // 34 KB    rows t0-30 .. t0+37

    // ---- stage v windows (zero-padded out of range) ----
    for (int idx = tid; idx < 1216 + 2176; idx += 256) {
        ushort* dst; int tt, srccol;
        if (idx < 1216) {
            int row = idx >> 5, ch = idx & 31;
            dst = &v0l[row][ch * 8]; tt = t0 - 15 + row; srccol = ch * 8;
        } else {
            int i2 = idx - 1216;
            int row = i2 >> 5, ch = i2 & 31;
            dst = &v1l[row][ch * 8]; tt = t0 - 30 + row; srccol = 256 + ch * 8;
        }
        bf16x8 v = {};
        if ((unsigned)tt < (unsigned)T)
            v = *reinterpret_cast<const bf16x8*>(v01 + ((size_t)(b * T + tt) * 512 + srccol));
        *reinterpret_cast<bf16x8*>(dst) = v;
    }

    // ---- scale softmax ----
    float s0 = scale_w[0], s1 = scale_w[1];
    float mxs = fmaxf(s0, s1);
    float e0 = __expf(s0 - mxs), e1 = __expf(s1 - mxs);
    float sw0 = e0 / (e0 + e1), sw1 = e1 / (e0 + e1);

    // ---- 64 softmax tasks (8 tok x 2 scale x 4 head), 4 lanes each ----
    {
        int task = tid >> 2, sub = tid & 3;
        int tok = task >> 3, rest = task & 7;
        int scale = rest >> 2, h = rest & 3;
        int bt = bt0 + tok;
        const float* lp; float* dst; int ctx; float sw;
        if (scale == 0) {
            lp = lg0 + (size_t)bt * N2_0 + h * CTX0;
            dst = &attw[tok][h * CTX0]; ctx = CTX0; sw = sw0;
        } else {
            lp = lg1 + (size_t)bt * N2_1 + h * CTX1;
            dst = &attw[tok][124 + h * CTX1]; ctx = CTX1; sw = sw1;
        }
        float mx = -1e30f;
        for (int c = sub; c < ctx; c += 4) mx = fmaxf(mx, lp[c]);
        mx = fmaxf(mx, __shfl_xor(mx, 1));
        mx = fmaxf(mx, __shfl_xor(mx, 2));
        float s = 0.f;
        for (int c = sub; c < ctx; c += 4) {
            float e = __expf(lp[c] - mx);
            dst[c] = e; s += e;
        }
        s += __shfl_xor(s, 1);
        s += __shfl_xor(s, 2);
        float scl = sw / s;
        for (int c = sub; c < ctx; c += 4) dst[c] *= scl;
    }
    __syncthreads();

    // ---- phase 2: windowed weighted sums from LDS ----
    const int tok = tid >> 5;
    const int f0  = (tid & 31) * 8;
    const int h   = f0 >> 6;

    float acc[8] = {};
    const float* a0 = &attw[tok][h * CTX0];
    const float* a1 = &attw[tok][124 + h * CTX1];

#pragma unroll 4
    for (int c = 0; c < CTX0; c++) {
        float w = a0[c];
        uint4 u = *reinterpret_cast<const uint4*>(&v0l[tok + c][f0]);
        acc[0] += w * asf(u.x << 16); acc[1] += w * asf(u.x & 0xffff0000u);
        acc[2] += w * asf(u.y << 16); acc[3] += w * asf(u.y & 0xffff0000u);
        acc[4] += w * asf(u.z << 16); acc[5] += w * asf(u.z & 0xffff0000u);
        acc[6] += w * asf(u.w << 16); acc[7] += w * asf(u.w & 0xffff0000u);
    }
#pragma unroll 4
    for (int c = 0; c < CTX1; c++) {
        float w = a1[c];
        uint4 u = *reinterpret_cast<const uint4*>(&v1l[tok + c][f0]);
        acc[0] += w * asf(u.x << 16); acc[1] += w * asf(u.x & 0xffff0000u);
        acc[2] += w * asf(u.y << 16); acc[3] += w * asf(u.y & 0xffff0000u);
        acc[4] += w * asf(u.z << 16); acc[5] += w * asf(u.z & 0xffff0000u);
        acc[6] += w * asf(u.w << 16); acc[7] += w * asf(u.w & 0xffff0000u);
    }

    ushort o[8];
#pragma unroll
    for (int j = 0; j < 8; j++) o[j] = f2bf(acc[j]);
    *reinterpret_cast<bf16x8*>(outc + (size_t)(bt0 + tok) * F + f0) =
        *reinterpret_cast<bf16x8*>(o);
}

// ---------------- host launcher ----------------
extern "C" void kernel_launch(void* const* d_in, const int* in_sizes, int n_in,
                              void* d_out, int out_size, void* d_ws, size_t ws_size,
                              hipStream_t stream)
{
    const float* Q    = (const float*)d_in[0];
    const float* V    = (const float*)d_in[2];
    const float* W1_0 = (const float*)d_in[3];
    const float* W1_1 = (const float*)d_in[4];
    const float* W2_0 = (const float*)d_in[5];
    const float* W2_1 = (const float*)d_in[6];
    const float* W3_0 = (const float*)d_in[7];
    const float* W3_1 = (const float*)d_in[8];
    const float* SW   = (const float*)d_in[9];
    const float* WO   = (const float*)d_in[10];

    // ---- carve workspace ----
    char* p = (char*)d_ws;
    auto carve = [&](size_t bytes) { char* r = p; p += (bytes + 255) & ~255ull; return r; };
    ushort* wt   = (ushort*)carve((size_t)WT_ROWS * K * 2);      // 844 KB
    ushort* qbf  = (ushort*)carve((size_t)M * K * 2);            // 4.2 MB
    ushort* vbf  = (ushort*)carve((size_t)M * K * 2);            // 4.2 MB
    ushort* q01  = (ushort*)carve((size_t)M * 512 * 2);          // 8.4 MB
    float*  lg0  = (float*) carve((size_t)M * N2_0 * 4);         // 4.06 MB
    float*  lg1  = (float*) carve((size_t)M * N2_1 * 4);         // 8.0 MB
    ushort* v01  = (ushort*)carve((size_t)M * 512 * 2);          // 8.4 MB
    ushort* ocb  = (ushort*)carve((size_t)M * F * 2);            // 4.2 MB
    (void)ws_size;

    const ushort* w1t  = wt;                                         // [512][256]
    const ushort* w2t0 = wt + (size_t)512 * K;                       // [124][256]
    const ushort* w2t1 = wt + (size_t)(512 + N2_0) * K;              // [244][256]
    const ushort* w3t  = wt + (size_t)(512 + N2_0 + N2_1) * K;       // [512][256]
    const ushort* wot  = wt + (size_t)(512 + N2_0 + N2_1 + 512) * K; // [256][256]

    // ---- 1) input/weight conversion ----
    {
        dim3 g(M * K / 8 / 256, 2);
        cvtqv_kernel<<<g, 256, 0, stream>>>(Q, V, qbf, vbf);
        int nthread = WT_ROWS * (K / 8);
        wcvt_kernel<<<(nthread + 255) / 256, 256, 0, stream>>>(
            WcvtArgs{ W1_0, W1_1, W2_0, W2_1, W3_0, W3_1, WO, wt });
    }

    // ---- 2) q01 = relu(Q @ [W1_0|W1_1]) ----
    gemm_kernel<ushort, true ><<<(M/64) * 8, 256, 0, stream>>>(qbf, K, w1t, q01, 512, 8);
    // ---- 3) logits ----
    gemm_kernel<float,  false><<<(M/64) * 2, 256, 0, stream>>>(q01,       512, w2t0, lg0, N2_0, 2);
    gemm_kernel<float,  false><<<(M/64) * 4, 256, 0, stream>>>(q01 + 256, 512, w2t1, lg1, N2_1, 4);
    // ---- 4) v01 = V @ [W3_0|W3_1] ----
    gemm_kernel<ushort, false><<<(M/64) * 8, 256, 0, stream>>>(vbf, K, w3t, v01, 512, 8);
    // ---- 5) softmax + windowed sum + scale combine ----
    attn_kernel<<<M / 8, 256, 0, stream>>>(lg0, lg1, v01, SW, ocb);
    // ---- 6) final @ w_out ----
    gemm_kernel<float,  false><<<(M/64) * 4, 256, 0, stream>>>(ocb, K, wot, (float*)d_out, F, 4);
}

// Round 4
// 159.140 us; speedup vs baseline: 2.4555x; 1.0735x over previous
//
#include <hip/hip_runtime.h>
#include <hip/hip_bf16.h>
#include <type_traits>

// ---------------- problem constants ----------------
static constexpr int BATCH = 2;
static constexpr int T     = 4096;
static constexpr int F     = 256;
static constexpr int M     = BATCH * T;   // 8192 rows
static constexpr int HPS   = 4;
static constexpr int CTX0  = 31, CTX1 = 61;
static constexpr int LGN   = 384;         // padded logits width (124 + 244 -> 368 -> 384)

typedef short bf16x8 __attribute__((ext_vector_type(8)));
typedef float f32x4  __attribute__((ext_vector_type(4)));

__device__ __forceinline__ ushort f2bf(float f) {
    union { float f; uint u; } v; v.f = f;
    uint u = v.u;
    return (ushort)((u + 0x7fffu + ((u >> 16) & 1u)) >> 16);   // RNE
}
__device__ __forceinline__ float asf(uint u) {
    union { uint u; float f; } v; v.u = u; return v.f;
}
__device__ __forceinline__ float bf2f(ushort u) { return asf(((uint)u) << 16); }

// ---------------- weight convert + transpose ----------------
// wt layout (bf16):
//   w1t   [512][256]  rows n: n<256 -> W1_0[:,n] else W1_1[:,n-256]
//   w2blk [384][512]  block-diag: r<124: k<256 -> W2_0[k][r] else 0
//                     124<=r<368: k>=256 -> W2_1[k-256][r-124] else 0 ; r>=368: 0
//   w3t   [512][256]  like w1t for W3
//   wot   [256][256]  WO^T
static constexpr size_t W1T_OFF  = 0;
static constexpr size_t W2B_OFF  = W1T_OFF + (size_t)512 * 256;
static constexpr size_t W3T_OFF  = W2B_OFF + (size_t)384 * 512;
static constexpr size_t WOT_OFF  = W3T_OFF + (size_t)512 * 256;
static constexpr size_t WT_ELEMS = WOT_OFF + (size_t)256 * 256;   // 524288

struct WcvtArgs {
    const float* w1_0; const float* w1_1;
    const float* w2_0; const float* w2_1;
    const float* w3_0; const float* w3_1;
    const float* wo;
    ushort* wt;
};

__global__ __launch_bounds__(256) void wcvt_kernel(WcvtArgs a) {
    int gid = blockIdx.x * 256 + threadIdx.x;          // one 8-elem chunk each
    if (gid >= (int)(WT_ELEMS / 8)) return;
    // section decode by chunk count: w1t 16384 | w2blk 24576 | w3t 16384 | wot 8192
    ushort o[8];
    if (gid < 16384 || (gid >= 16384 + 24576 && gid < 16384 + 24576 + 16384)) {
        bool w3 = gid >= 16384;
        int g = w3 ? gid - (16384 + 24576) : gid;
        int row = g >> 5;                 // 512 rows, 32 chunks each
        int kk  = (g & 31) * 8;
        const float* src = (row < 256) ? (w3 ? a.w3_0 : a.w1_0) : (w3 ? a.w3_1 : a.w1_1);
        int col = row & 255;
#pragma unroll
        for (int j = 0; j < 8; j++) o[j] = f2bf(src[(size_t)(kk + j) * 256 + col]);
        size_t base = (w3 ? W3T_OFF : W1T_OFF) + (size_t)row * 256 + kk;
        *reinterpret_cast<bf16x8*>(a.wt + base) = *reinterpret_cast<bf16x8*>(o);
    } else if (gid < 16384 + 24576) {
        int g = gid - 16384;
        int row = g >> 6;                 // 384 rows, 64 chunks each (K=512)
        int kk  = (g & 63) * 8;
#pragma unroll
        for (int j = 0; j < 8; j++) {
            int k = kk + j;
            float v = 0.f;
            if (row < 124) { if (k < 256) v = a.w2_0[(size_t)k * 124 + row]; }
            else if (row < 368) { if (k >= 256) v = a.w2_1[(size_t)(k - 256) * 244 + (row - 124)]; }
            o[j] = f2bf(v);
        }
        *reinterpret_cast<bf16x8*>(a.wt + W2B_OFF + (size_t)row * 512 + kk) =
            *reinterpret_cast<bf16x8*>(o);
    } else {
        int g = gid - (16384 + 24576 + 16384);
        int row = g >> 5;
        int kk  = (g & 31) * 8;
#pragma unroll
        for (int j = 0; j < 8; j++) o[j] = f2bf(a.wo[(size_t)(kk + j) * 256 + row]);
        *reinterpret_cast<bf16x8*>(a.wt + WOT_OFF + (size_t)row * 256 + kk) =
            *reinterpret_cast<bf16x8*>(o);
    }
}

// ---------------- bf16 MFMA GEMM, 64x64 tile, K-halves of 128 ----------------
// AMODE: 0 = A bf16, 1 = A fp32 (convert while staging), 2 = A,A2 bf16 (sum)
template <int KTOT, int AMODE, typename OutT, bool RELU>
__global__ __launch_bounds__(256, 4) void gemm_kernel(
    const void* __restrict__ Av, const void* __restrict__ A2v, int lda,
    const ushort* __restrict__ Bt,   // [N][KTOT] bf16
    OutT* __restrict__ C, int N, int ncb)
{
    __shared__ ushort Al[64][128];   // 16 KB, chunk ch at ch^(row&7)
    __shared__ ushort Bl[64][128];   // 16 KB

    const int tid = threadIdx.x;
    const int nwg = gridDim.x;
    const int lin = blockIdx.x;
    const int qq  = nwg >> 3;                       // nwg % 8 == 0 always
    const int swz = (lin & 7) * qq + (lin >> 3);
    const int cb  = swz % ncb;
    const int rb  = swz / ncb;
    const int m0  = rb * 64;
    const int n0  = cb * 64;

    const ushort* Ab  = (const ushort*)Av;
    const float*  Af  = (const float*)Av;
    const ushort* A2b = (const ushort*)A2v;

    const int wave = tid >> 6, lane = tid & 63;
    const int wr = wave >> 1, wc = wave & 1;
    const int l15 = lane & 15, l4 = lane >> 4;

    f32x4 acc[2][2] = {};

    for (int kh = 0; kh < KTOT / 128; kh++) {
        // ---- stage A half-tile 64x128 ----
#pragma unroll
        for (int it = 0; it < 4; it++) {
            int i = it * 256 + tid;
            int row = i >> 4, ch = i & 15;
            int k = kh * 128 + ch * 8;
            bf16x8 v;
            if constexpr (AMODE == 0) {
                v = *reinterpret_cast<const bf16x8*>(Ab + (size_t)(m0 + row) * lda + k);
            } else if constexpr (AMODE == 1) {
                const float* ap = Af + (size_t)(m0 + row) * lda + k;
                float4 x = *reinterpret_cast<const float4*>(ap);
                float4 y = *reinterpret_cast<const float4*>(ap + 4);
                ushort o[8] = { f2bf(x.x), f2bf(x.y), f2bf(x.z), f2bf(x.w),
                                f2bf(y.x), f2bf(y.y), f2bf(y.z), f2bf(y.w) };
                v = *reinterpret_cast<bf16x8*>(o);
            } else {
                bf16x8 p = *reinterpret_cast<const bf16x8*>(Ab  + (size_t)(m0 + row) * lda + k);
                bf16x8 q = *reinterpret_cast<const bf16x8*>(A2b + (size_t)(m0 + row) * lda + k);
                ushort o[8];
#pragma unroll
                for (int j = 0; j < 8; j++)
                    o[j] = f2bf(bf2f((ushort)p[j]) + bf2f((ushort)q[j]));
                v = *reinterpret_cast<bf16x8*>(o);
            }
            *reinterpret_cast<bf16x8*>(&Al[row][(ch ^ (row & 7)) * 8]) = v;
        }
        // ---- stage B half-tile 64x128 ----
#pragma unroll
        for (int it = 0; it < 4; it++) {
            int i = it * 256 + tid;
            int row = i >> 4, ch = i & 15;
            int k = kh * 128 + ch * 8;
            bf16x8 v = *reinterpret_cast<const bf16x8*>(Bt + (size_t)(n0 + row) * KTOT + k);
            *reinterpret_cast<bf16x8*>(&Bl[row][(ch ^ (row & 7)) * 8]) = v;
        }
        __syncthreads();

#pragma unroll
        for (int s = 0; s < 4; s++) {
            bf16x8 af[2], bfr[2];
#pragma unroll
            for (int i = 0; i < 2; i++) {
                int row = wr * 32 + i * 16 + l15;
                int ch  = (s * 4 + l4) ^ (row & 7);
                af[i] = *reinterpret_cast<const bf16x8*>(&Al[row][ch * 8]);
            }
#pragma unroll
            for (int j = 0; j < 2; j++) {
                int row = wc * 32 + j * 16 + l15;
                int ch  = (s * 4 + l4) ^ (row & 7);
                bfr[j] = *reinterpret_cast<const bf16x8*>(&Bl[row][ch * 8]);
            }
#pragma unroll
            for (int i = 0; i < 2; i++)
#pragma unroll
                for (int j = 0; j < 2; j++)
                    acc[i][j] = __builtin_amdgcn_mfma_f32_16x16x32_bf16(af[i], bfr[j], acc[i][j], 0, 0, 0);
        }
        __syncthreads();
    }

    // epilogue: C/D layout col = lane&15, row = (lane>>4)*4 + reg
#pragma unroll
    for (int i = 0; i < 2; i++)
#pragma unroll
        for (int j = 0; j < 2; j++) {
            int col = n0 + wc * 32 + j * 16 + l15;
#pragma unroll
            for (int r = 0; r < 4; r++) {
                int row = m0 + wr * 32 + i * 16 + l4 * 4 + r;
                float v = acc[i][j][r];
                if (RELU) v = fmaxf(v, 0.0f);
                if constexpr (std::is_same<OutT, ushort>::value)
                    C[(size_t)row * N + col] = f2bf(v);
                else
                    C[(size_t)row * N + col] = v;
            }
        }
}

// ---------------- per-scale windowed attention ----------------
// 32 tokens / block. Stage v_s window (32+2*HALO rows) in LDS; softmax for
// 128 (tok,head) tasks with 2 lanes each; windowed sums with sw_s folded.
template <int SCALE>
__global__ __launch_bounds__(256) void attn_kernel(
    const float*  __restrict__ lg,    // [M][384] f32 (cols 0..123 s0, 124..367 s1)
    const ushort* __restrict__ v01,   // [M][512] bf16 (s0: cols 0..255, s1: 256..511)
    const float*  __restrict__ scale_w,
    ushort*       __restrict__ p)     // [M][256] bf16, sw_s * attn-out
{
    constexpr int CTX  = SCALE ? CTX1 : CTX0;
    constexpr int HALO = (CTX - 1) / 2;
    constexpr int VR   = 32 + 2 * HALO;          // 62 / 92
    constexpr int LGO  = SCALE ? 124 : 0;
    constexpr int VOFF = SCALE ? 256 : 0;

    __shared__ ushort vl[VR][256];               // 31/46 KB
    __shared__ float  att[32][HPS * CTX];        // 15.5/30.5 KB

    const int tid = threadIdx.x;
    const int nwg = gridDim.x;
    const int lin = blockIdx.x;
    const int qq  = nwg >> 3;
    const int swz = (lin & 7) * qq + (lin >> 3);
    const int bt0 = swz * 32;
    const int b   = bt0 >> 12;
    const int t0  = bt0 & (T - 1);

    // ---- stage v window (zero-padded OOB) ----
    for (int i = tid; i < VR * 32; i += 256) {
        int row = i >> 5, ch = i & 31;
        int tt = t0 - HALO + row;
        bf16x8 v = {};
        if ((unsigned)tt < (unsigned)T)
            v = *reinterpret_cast<const bf16x8*>(
                v01 + ((size_t)(b * T + tt) * 512 + VOFF + ch * 8));
        *reinterpret_cast<bf16x8*>(&vl[row][ch * 8]) = v;
    }

    // ---- scale weight softmax ----
    float s0 = scale_w[0], s1 = scale_w[1];
    float mxs = fmaxf(s0, s1);
    float e0 = __expf(s0 - mxs), e1 = __expf(s1 - mxs);
    float sw = (SCALE ? e1 : e0) / (e0 + e1);

    // ---- softmax: 128 tasks (32 tok x 4 head), 2 lanes each ----
    {
        int task = tid >> 1, sub = tid & 1;
        int tok = task >> 2, h = task & 3;
        const float* lp = lg + (size_t)(bt0 + tok) * LGN + LGO + h * CTX;
        float* dst = &att[tok][h * CTX];
        float mx = -1e30f;
        for (int c = sub; c < CTX; c += 2) mx = fmaxf(mx, lp[c]);
        mx = fmaxf(mx, __shfl_xor(mx, 1));
        float s = 0.f;
        for (int c = sub; c < CTX; c += 2) {
            float e = __expf(lp[c] - mx);
            dst[c] = e; s += e;
        }
        s += __shfl_xor(s, 1);
        float scl = sw / s;
        for (int c = sub; c < CTX; c += 2) dst[c] *= scl;
    }
    __syncthreads();

    // ---- windowed sums: 4 rounds of (8 tok x 32 feat-groups) ----
    const int w  = tid >> 5;
    const int f0 = (tid & 31) * 8;
    const int h  = f0 >> 6;

#pragma unroll 1
    for (int tk = 0; tk < 4; tk++) {
        int tok = tk * 8 + w;
        const float* aw = &att[tok][h * CTX];
        float acc[8] = {};
#pragma unroll 4
        for (int c = 0; c < CTX; c++) {
            float wv = aw[c];
            uint4 u = *reinterpret_cast<const uint4*>(&vl[tok + c][f0]);
            acc[0] += wv * asf(u.x << 16); acc[1] += wv * asf(u.x & 0xffff0000u);
            acc[2] += wv * asf(u.y << 16); acc[3] += wv * asf(u.y & 0xffff0000u);
            acc[4] += wv * asf(u.z << 16); acc[5] += wv * asf(u.z & 0xffff0000u);
            acc[6] += wv * asf(u.w << 16); acc[7] += wv * asf(u.w & 0xffff0000u);
        }
        ushort o[8];
#pragma unroll
        for (int j = 0; j < 8; j++) o[j] = f2bf(acc[j]);
        *reinterpret_cast<bf16x8*>(p + (size_t)(bt0 + tok) * F + f0) =
            *reinterpret_cast<bf16x8*>(o);
    }
}

// ---------------- host launcher ----------------
extern "C" void kernel_launch(void* const* d_in, const int* in_sizes, int n_in,
                              void* d_out, int out_size, void* d_ws, size_t ws_size,
                              hipStream_t stream)
{
    const float* Q    = (const float*)d_in[0];
    const float* V    = (const float*)d_in[2];
    const float* W1_0 = (const float*)d_in[3];
    const float* W1_1 = (const float*)d_in[4];
    const float* W2_0 = (const float*)d_in[5];
    const float* W2_1 = (const float*)d_in[6];
    const float* W3_0 = (const float*)d_in[7];
    const float* W3_1 = (const float*)d_in[8];
    const float* SW   = (const float*)d_in[9];
    const float* WO   = (const float*)d_in[10];

    // ---- carve workspace ----
    char* pws = (char*)d_ws;
    auto carve = [&](size_t bytes) { char* r = pws; pws += (bytes + 255) & ~255ull; return r; };
    ushort* wt  = (ushort*)carve(WT_ELEMS * 2);           // 1.0 MB
    ushort* q01 = (ushort*)carve((size_t)M * 512 * 2);    // 8.4 MB
    float*  lg  = (float*) carve((size_t)M * LGN * 4);    // 12.6 MB
    ushort* v01 = (ushort*)carve((size_t)M * 512 * 2);    // 8.4 MB
    ushort* p0  = (ushort*)carve((size_t)M * F * 2);      // 4.2 MB
    ushort* p1  = (ushort*)carve((size_t)M * F * 2);      // 4.2 MB
    (void)ws_size;

    const ushort* w1t   = wt + W1T_OFF;
    const ushort* w2blk = wt + W2B_OFF;
    const ushort* w3t   = wt + W3T_OFF;
    const ushort* wot   = wt + WOT_OFF;

    // 1) weights: convert + transpose + block-diag pack
    wcvt_kernel<<<(int)(WT_ELEMS / 8 / 256), 256, 0, stream>>>(
        WcvtArgs{ W1_0, W1_1, W2_0, W2_1, W3_0, W3_1, WO, wt });

    // 2) q01 = relu(Q @ [W1_0|W1_1])   (fp32 A converted in staging)
    gemm_kernel<256, 1, ushort, true ><<<(M/64) * 8, 256, 0, stream>>>(
        Q, nullptr, 256, w1t, q01, 512, 8);
    // 3) v01 = V @ [W3_0|W3_1]
    gemm_kernel<256, 1, ushort, false><<<(M/64) * 8, 256, 0, stream>>>(
        V, nullptr, 256, w3t, v01, 512, 8);
    // 4) lg = q01 @ W2blk  (block-diagonal, both scales at once)
    gemm_kernel<512, 0, float,  false><<<(M/64) * 6, 256, 0, stream>>>(
        q01, nullptr, 512, w2blk, lg, LGN, 6);
    // 5) per-scale attention partials
    attn_kernel<0><<<M / 32, 256, 0, stream>>>(lg, v01, SW, p0);
    attn_kernel<1><<<M / 32, 256, 0, stream>>>(lg, v01, SW, p1);
    // 6) out = (p0 + p1) @ WO
    gemm_kernel<256, 2, float,  false><<<(M/64) * 4, 256, 0, stream>>>(
        p0, p1, 256, wot, (float*)d_out, 256, 4);
}

// Round 5
// 140.546 us; speedup vs baseline: 2.7803x; 1.1323x over previous
//
#include <hip/hip_runtime.h>
#include <hip/hip_bf16.h>
#include <type_traits>

// ---------------- problem constants ----------------
static constexpr int T    = 4096;
static constexpr int F    = 256;
static constexpr int M    = 2 * T;        // 8192 rows
static constexpr int HPS  = 4;
static constexpr int CTX0 = 31, CTX1 = 61;
static constexpr int LGN  = 384;          // padded logits width (368 used)

typedef short bf16x8 __attribute__((ext_vector_type(8)));
typedef float f32x4  __attribute__((ext_vector_type(4)));

__device__ __forceinline__ ushort f2bf(float f) {
    union { float f; uint u; } v; v.f = f;
    uint u = v.u;
    return (ushort)((u + 0x7fffu + ((u >> 16) & 1u)) >> 16);   // RNE
}
__device__ __forceinline__ float asf(uint u) {
    union { uint u; float f; } v; v.u = u; return v.f;
}
__device__ __forceinline__ float bf2f(ushort u) { return asf(((uint)u) << 16); }

// ---------------- packed transposed weights in ws ----------------
// w1t[512][256] | w2blk[384][512] (block-diag) | w3t[512][256] | wot[256][256]
static constexpr size_t W1T_OFF  = 0;
static constexpr size_t W2B_OFF  = W1T_OFF + (size_t)512 * 256;
static constexpr size_t W3T_OFF  = W2B_OFF + (size_t)384 * 512;
static constexpr size_t WOT_OFF  = W3T_OFF + (size_t)512 * 256;
static constexpr size_t WT_ELEMS = WOT_OFF + (size_t)256 * 256;

struct WArgs {
    const float* w1_0; const float* w1_1;
    const float* w2_0; const float* w2_1;
    const float* w3_0; const float* w3_1;
    const float* wo;
    ushort* wt;
};

// One 64x64 dst tile per block. Phase 1: coalesced fp32 read into LDS
// ([k][n], padded). Phase 2: transposed bf16x8 write.
// blocks 0-15 W1_0 | 16-31 W1_1 | 32-47 W3_0 | 48-63 W3_1 | 64-79 WO |
// 80-127: w2blk 48 tiles (6 n-tiles x 8 k-tiles), zero/blk-diag per element.
__global__ __launch_bounds__(256) void wprep_kernel(WArgs a) {
    __shared__ float tb[64][72];
    const int tid = threadIdx.x;
    const int blk = blockIdx.x;

    const float* src = nullptr;
    ushort* dst; int dstLD, k0, nbase; bool isw2 = false;

    if (blk < 64) {
        int sec = blk >> 4;                   // 0 W1_0, 1 W1_1, 2 W3_0, 3 W3_1
        int tt = blk & 15, kt = tt >> 2, nt = tt & 3;
        k0 = kt * 64;
        src = (sec == 0) ? a.w1_0 : (sec == 1) ? a.w1_1 : (sec == 2) ? a.w3_0 : a.w3_1;
        dst = a.wt + ((sec < 2) ? W1T_OFF : W3T_OFF);
        nbase = (sec & 1) * 256 + nt * 64;
        dstLD = 256;
    } else if (blk < 80) {
        int tt = blk - 64, kt = tt >> 2, nt = tt & 3;
        k0 = kt * 64; src = a.wo; dst = a.wt + WOT_OFF; nbase = nt * 64; dstLD = 256;
    } else {
        int tt = blk - 80;                    // 6 x 8
        int nt = tt >> 3, kt = tt & 7;
        k0 = kt * 64; nbase = nt * 64; dst = a.wt + W2B_OFF; dstLD = 512; isw2 = true;
    }

    // phase 1: tb[k][n] = src[k0+k][n0+n]
    {
        int kk = tid >> 2;                    // 0..63
        int c4 = (tid & 3) * 16;              // 16 cols per thread
        if (!isw2) {
            int ncol0 = (blk < 64) ? (nbase & 255) : nbase;
            const float* sp = src + (size_t)(k0 + kk) * 256 + ncol0 + c4;
#pragma unroll
            for (int ii = 0; ii < 4; ii++) {
                float4 v = *reinterpret_cast<const float4*>(sp + ii * 4);
                tb[kk][c4 + ii * 4 + 0] = v.x; tb[kk][c4 + ii * 4 + 1] = v.y;
                tb[kk][c4 + ii * 4 + 2] = v.z; tb[kk][c4 + ii * 4 + 3] = v.w;
            }
        } else {
            int k = k0 + kk;
#pragma unroll 4
            for (int ii = 0; ii < 16; ii++) {
                int n = nbase + c4 + ii;      // w2blk row (n-dim)
                float v = 0.f;
                if (n < 124) { if (k < 256) v = a.w2_0[(size_t)k * 124 + n]; }
                else if (n < 368) { if (k >= 256) v = a.w2_1[(size_t)(k - 256) * 244 + (n - 124)]; }
                tb[kk][c4 + ii] = v;
            }
        }
    }
    __syncthreads();

    // phase 2: dst[nbase+n][k0 + ch*8 .. +8] = tb[ch*8+j][n]
#pragma unroll
    for (int it = 0; it < 2; it++) {
        int slot = it * 256 + tid;
        int n = slot >> 3, ch = slot & 7;
        ushort o[8];
#pragma unroll
        for (int j = 0; j < 8; j++) o[j] = f2bf(tb[ch * 8 + j][n]);
        *reinterpret_cast<bf16x8*>(dst + (size_t)(nbase + n) * dstLD + k0 + ch * 8) =
            *reinterpret_cast<bf16x8*>(o);
    }
}

// ---------------- 128x128 double-buffered bf16 MFMA GEMM ----------------
// 256 threads = 4 waves (2x2), wave owns 64x64 = 4x4 16x16 frags.
// BK=64, LDS XOR-swizzled, one barrier + 32 MFMA/wave per K-step.
// AMODE: 0 = A bf16 | 1 = A fp32 (convert in staging) | 2 = A+A2 bf16 sum.
// NPAIR=2: blockIdx splits into two independent problems (A/B/C/relu per half).
struct GemmArgs {
    const void* A0; const void* A1; const void* A2;
    const ushort* B0; const ushort* B1;
    void* C0; void* C1;
    int lda, N, ncb, relu0, relu1;
};

template <int KTOT, int AMODE, int NPAIR, typename OutT>
__global__ __launch_bounds__(256, 2) void gemm128_kernel(GemmArgs a) {
    __shared__ ushort Al[2][128][64];   // 32 KB
    __shared__ ushort Bl[2][128][64];   // 32 KB

    const int tid = threadIdx.x;
    int lin = blockIdx.x;
    int half = gridDim.x;
    int sel = 0;
    if constexpr (NPAIR == 2) {
        half >>= 1;
        sel = lin >= half;
        lin -= sel * half;
    }
    const int qq  = half >> 3;                      // half % 8 == 0 always
    const int swz = (lin & 7) * qq + (lin >> 3);    // bijective XCD remap
    const int cb  = swz % a.ncb;
    const int rb  = swz / a.ncb;
    const int m0  = rb * 128;
    const int n0  = cb * 128;

    const void*   Av  = sel ? a.A1 : a.A0;
    const ushort* Bt  = sel ? a.B1 : a.B0;
    OutT*         C   = (OutT*)(sel ? a.C1 : a.C0);
    const bool    relu = sel ? (a.relu1 != 0) : (a.relu0 != 0);
    const int     lda = a.lda, N = a.N;

    const int wave = tid >> 6, lane = tid & 63;
    const int wr = wave >> 1, wc = wave & 1;
    const int l15 = lane & 15, l4 = lane >> 4;
    const int srow = tid >> 3;          // staging row base (0..31)
    const int sch  = tid & 7;           // staging chunk

    float4 pAf[4][2];   // AMODE 1
    bf16x8 pAb[4];      // AMODE 0/2
    bf16x8 pA2[4];      // AMODE 2
    bf16x8 pB[4];

    auto loadRegs = [&](int s) {
        const int k0 = s * 64;
#pragma unroll
        for (int it = 0; it < 4; it++) {
            int row = it * 32 + srow;
            if constexpr (AMODE == 1) {
                const float* ap = (const float*)Av + (size_t)(m0 + row) * lda + k0 + sch * 8;
                pAf[it][0] = *reinterpret_cast<const float4*>(ap);
                pAf[it][1] = *reinterpret_cast<const float4*>(ap + 4);
            } else {
                pAb[it] = *reinterpret_cast<const bf16x8*>(
                    (const ushort*)Av + (size_t)(m0 + row) * lda + k0 + sch * 8);
                if constexpr (AMODE == 2)
                    pA2[it] = *reinterpret_cast<const bf16x8*>(
                        (const ushort*)a.A2 + (size_t)(m0 + row) * lda + k0 + sch * 8);
            }
            pB[it] = *reinterpret_cast<const bf16x8*>(
                Bt + (size_t)(n0 + row) * KTOT + k0 + sch * 8);
        }
    };
    auto writeLds = [&](int buf) {
#pragma unroll
        for (int it = 0; it < 4; it++) {
            int row = it * 32 + srow;
            int c8  = (sch ^ (row & 7)) * 8;
            bf16x8 av;
            if constexpr (AMODE == 1) {
                ushort o[8] = { f2bf(pAf[it][0].x), f2bf(pAf[it][0].y),
                                f2bf(pAf[it][0].z), f2bf(pAf[it][0].w),
                                f2bf(pAf[it][1].x), f2bf(pAf[it][1].y),
                                f2bf(pAf[it][1].z), f2bf(pAf[it][1].w) };
                av = *reinterpret_cast<bf16x8*>(o);
            } else if constexpr (AMODE == 2) {
                ushort o[8];
#pragma unroll
                for (int j = 0; j < 8; j++)
                    o[j] = f2bf(bf2f((ushort)pAb[it][j]) + bf2f((ushort)pA2[it][j]));
                av = *reinterpret_cast<bf16x8*>(o);
            } else {
                av = pAb[it];
            }
            *reinterpret_cast<bf16x8*>(&Al[buf][row][c8]) = av;
            *reinterpret_cast<bf16x8*>(&Bl[buf][row][c8]) = pB[it];
        }
    };

    f32x4 acc[4][4] = {};

    loadRegs(0);
    writeLds(0);
    constexpr int NST = KTOT / 64;
#pragma unroll
    for (int s = 0; s < NST; s++) {
        if (s + 1 < NST) loadRegs(s + 1);
        __syncthreads();
        if (s + 1 < NST) writeLds((s + 1) & 1);
        const int buf = s & 1;
#pragma unroll
        for (int ks = 0; ks < 2; ks++) {
            bf16x8 af[4], bv[4];
#pragma unroll
            for (int i = 0; i < 4; i++) {
                int row = wr * 64 + i * 16 + l15;
                int ch  = (ks * 4 + l4) ^ (row & 7);
                af[i] = *reinterpret_cast<const bf16x8*>(&Al[buf][row][ch * 8]);
            }
#pragma unroll
            for (int j = 0; j < 4; j++) {
                int row = wc * 64 + j * 16 + l15;
                int ch  = (ks * 4 + l4) ^ (row & 7);
                bv[j] = *reinterpret_cast<const bf16x8*>(&Bl[buf][row][ch * 8]);
            }
#pragma unroll
            for (int i = 0; i < 4; i++)
#pragma unroll
                for (int j = 0; j < 4; j++)
                    acc[i][j] = __builtin_amdgcn_mfma_f32_16x16x32_bf16(af[i], bv[j], acc[i][j], 0, 0, 0);
        }
    }

    // epilogue: C/D layout col = lane&15, row = (lane>>4)*4 + reg (m89-verified)
#pragma unroll
    for (int i = 0; i < 4; i++)
#pragma unroll
        for (int j = 0; j < 4; j++) {
            int col = n0 + wc * 64 + j * 16 + l15;
#pragma unroll
            for (int r = 0; r < 4; r++) {
                int row = m0 + wr * 64 + i * 16 + l4 * 4 + r;
                float v = acc[i][j][r];
                if (relu) v = fmaxf(v, 0.0f);
                if constexpr (std::is_same<OutT, ushort>::value)
                    C[(size_t)row * N + col] = f2bf(v);
                else
                    C[(size_t)row * N + col] = v;
            }
        }
}

// ---------------- windowed attention, both scales in one dispatch ----------------
// 32 tokens/block; first half of grid = scale0, second = scale1.
__global__ __launch_bounds__(256) void attn_kernel(
    const float*  __restrict__ lg,    // [M][384] (0..123 s0, 124..367 s1)
    const ushort* __restrict__ v01,   // [M][512] (s0 cols 0..255, s1 256..511)
    const float*  __restrict__ scale_w,
    ushort*       __restrict__ p0,    // [M][256] sw0 * attn0
    ushort*       __restrict__ p1)    // [M][256] sw1 * attn1
{
    __shared__ ushort vl[92][256];    // 46 KB (union; scale0 uses 62 rows)
    __shared__ float  att[32][HPS * CTX1];  // 30.5 KB

    const int tid  = threadIdx.x;
    const int half = gridDim.x >> 1;
    int lin = blockIdx.x;
    const int sc = lin >= half;
    lin -= sc * half;
    const int qq  = half >> 3;
    const int swz = (lin & 7) * qq + (lin >> 3);
    const int bt0 = swz * 32;
    const int b   = bt0 >> 12;
    const int t0  = bt0 & (T - 1);

    const int CTX  = sc ? CTX1 : CTX0;
    const int HALO = (CTX - 1) >> 1;
    const int VR   = 32 + 2 * HALO;       // 62 / 92
    const int LGO  = sc ? 124 : 0;
    const int VOFF = sc ? 256 : 0;
    ushort* p = sc ? p1 : p0;

    // stage v window (zero-padded OOB)
    for (int i = tid; i < VR * 32; i += 256) {
        int row = i >> 5, ch = i & 31;
        int tt = t0 - HALO + row;
        bf16x8 v = {};
        if ((unsigned)tt < (unsigned)T)
            v = *reinterpret_cast<const bf16x8*>(
                v01 + ((size_t)(b * T + tt) * 512 + VOFF + ch * 8));
        *reinterpret_cast<bf16x8*>(&vl[row][ch * 8]) = v;
    }

    // scale-weight softmax
    float s0 = scale_w[0], s1 = scale_w[1];
    float mxs = fmaxf(s0, s1);
    float e0 = __expf(s0 - mxs), e1 = __expf(s1 - mxs);
    float sw = (sc ? e1 : e0) / (e0 + e1);

    // head softmax: 128 tasks (32 tok x 4 head), 2 lanes each
    {
        int task = tid >> 1, sub = tid & 1;
        int tok = task >> 2, h = task & 3;
        const float* lp = lg + (size_t)(bt0 + tok) * LGN + LGO + h * CTX;
        float* dst = &att[tok][h * CTX];
        float mx = -1e30f;
        for (int c = sub; c < CTX; c += 2) mx = fmaxf(mx, lp[c]);
        mx = fmaxf(mx, __shfl_xor(mx, 1));
        float s = 0.f;
        for (int c = sub; c < CTX; c += 2) {
            float e = __expf(lp[c] - mx);
            dst[c] = e; s += e;
        }
        s += __shfl_xor(s, 1);
        float scl = sw / s;
        for (int c = sub; c < CTX; c += 2) dst[c] *= scl;
    }
    __syncthreads();

    // windowed sums: 4 rounds of (8 tok x 32 feat-groups)
    const int w  = tid >> 5;
    const int f0 = (tid & 31) * 8;
    const int h  = f0 >> 6;

#pragma unroll 1
    for (int tk = 0; tk < 4; tk++) {
        int tok = tk * 8 + w;
        const float* aw = &att[tok][h * CTX];
        float acc[8] = {};
#pragma unroll 4
        for (int c = 0; c < CTX; c++) {
            float wv = aw[c];
            uint4 u = *reinterpret_cast<const uint4*>(&vl[tok + c][f0]);
            acc[0] += wv * asf(u.x << 16); acc[1] += wv * asf(u.x & 0xffff0000u);
            acc[2] += wv * asf(u.y << 16); acc[3] += wv * asf(u.y & 0xffff0000u);
            acc[4] += wv * asf(u.z << 16); acc[5] += wv * asf(u.z & 0xffff0000u);
            acc[6] += wv * asf(u.w << 16); acc[7] += wv * asf(u.w & 0xffff0000u);
        }
        ushort o[8];
#pragma unroll
        for (int j = 0; j < 8; j++) o[j] = f2bf(acc[j]);
        *reinterpret_cast<bf16x8*>(p + (size_t)(bt0 + tok) * F + f0) =
            *reinterpret_cast<bf16x8*>(o);
    }
}

// ---------------- host launcher ----------------
extern "C" void kernel_launch(void* const* d_in, const int* in_sizes, int n_in,
                              void* d_out, int out_size, void* d_ws, size_t ws_size,
                              hipStream_t stream)
{
    const float* Q    = (const float*)d_in[0];
    const float* V    = (const float*)d_in[2];
    const float* W1_0 = (const float*)d_in[3];
    const float* W1_1 = (const float*)d_in[4];
    const float* W2_0 = (const float*)d_in[5];
    const float* W2_1 = (const float*)d_in[6];
    const float* W3_0 = (const float*)d_in[7];
    const float* W3_1 = (const float*)d_in[8];
    const float* SW   = (const float*)d_in[9];
    const float* WO   = (const float*)d_in[10];

    char* pws = (char*)d_ws;
    auto carve = [&](size_t bytes) { char* r = pws; pws += (bytes + 255) & ~255ull; return r; };
    ushort* wt  = (ushort*)carve(WT_ELEMS * 2);           // 1.0 MB
    ushort* q01 = (ushort*)carve((size_t)M * 512 * 2);    // 8.4 MB
    float*  lg  = (float*) carve((size_t)M * LGN * 4);    // 12.6 MB
    ushort* v01 = (ushort*)carve((size_t)M * 512 * 2);    // 8.4 MB
    ushort* p0  = (ushort*)carve((size_t)M * F * 2);      // 4.2 MB
    ushort* p1  = (ushort*)carve((size_t)M * F * 2);      // 4.2 MB
    (void)ws_size;

    const ushort* w1t   = wt + W1T_OFF;
    const ushort* w2blk = wt + W2B_OFF;
    const ushort* w3t   = wt + W3T_OFF;
    const ushort* wot   = wt + WOT_OFF;

    // 1) weight transpose/pack (coalesced)
    wprep_kernel<<<128, 256, 0, stream>>>(
        WArgs{ W1_0, W1_1, W2_0, W2_1, W3_0, W3_1, WO, wt });

    // 2) paired: q01 = relu(Q @ W1cat), v01 = V @ W3cat   (fp32 A)
    {
        GemmArgs ga{};
        ga.A0 = Q;  ga.A1 = V;  ga.A2 = nullptr;
        ga.B0 = w1t; ga.B1 = w3t;
        ga.C0 = q01; ga.C1 = v01;
        ga.lda = 256; ga.N = 512; ga.ncb = 4; ga.relu0 = 1; ga.relu1 = 0;
        gemm128_kernel<256, 1, 2, ushort><<<512, 256, 0, stream>>>(ga);
    }
    // 3) lg = q01 @ w2blk  (block-diagonal both scales)
    {
        GemmArgs ga{};
        ga.A0 = q01; ga.B0 = w2blk; ga.C0 = lg;
        ga.lda = 512; ga.N = LGN; ga.ncb = 3; ga.relu0 = 0;
        gemm128_kernel<512, 0, 1, float><<<192, 256, 0, stream>>>(ga);
    }
    // 4) attention partials, both scales
    attn_kernel<<<512, 256, 0, stream>>>(lg, v01, SW, p0, p1);
    // 5) out = (p0 + p1) @ WO
    {
        GemmArgs ga{};
        ga.A0 = p0; ga.A2 = p1; ga.B0 = wot; ga.C0 = d_out;
        ga.lda = 256; ga.N = 256; ga.ncb = 2; ga.relu0 = 0;
        gemm128_kernel<256, 2, 1, float><<<128, 256, 0, stream>>>(ga);
    }
}